// Round 1
// baseline (927.959 us; speedup 1.0000x reference)
//
#include <hip/hip_runtime.h>
#include <hip/hip_bf16.h>
#include <cstdint>

// Problem constants (from reference)
#define N_NODES 100000
#define N_EDGES 1600000
#define D_IN    128
#define D_H     64
#define D_OUT   16

// ---------------------------------------------------------------------------
// Workspace layout (bytes, 128-aligned):
//   counts   : N int32            @ 0          (400000)
//   offsets  : N+1 int32          @ 400128     (400004)
//   cursors  : N int32            @ 800256     (400000)
//   dinv     : N float            @ 1200256    (400000)
//   srcs     : E int32 (CSR)      @ 1600256    (6400000)
//   hs       : N*64 bf16          @ 8000256    (12800000)
//   relu_buf : N*64 float         @ 20800256   (25600000)
//   h2s      : N*16 float         @ 46400256   (6400000)
// total ~52.8 MB
// ---------------------------------------------------------------------------

__global__ void zero_kernel(int* __restrict__ p, int n) {
    int i = blockIdx.x * 256 + threadIdx.x;
    if (i < n) p[i] = 0;
}

__global__ void hist_kernel(const int* __restrict__ dst, int* __restrict__ counts) {
    int i = blockIdx.x * blockDim.x + threadIdx.x;
    int stride = gridDim.x * blockDim.x;
    for (int e = i; e < N_EDGES; e += stride)
        atomicAdd(&counts[dst[e]], 1);
}

// Single-block exclusive scan over counts -> offsets/cursors, plus dinv.
__global__ __launch_bounds__(1024) void scan_kernel(const int* __restrict__ counts,
                                                    int* __restrict__ offsets,
                                                    int* __restrict__ cursors,
                                                    float* __restrict__ dinv) {
    __shared__ int partial[1024];
    const int T = 1024;
    int t = threadIdx.x;
    const int chunk = (N_NODES + T - 1) / T;  // 98
    int lo = t * chunk;
    int hi = lo + chunk; if (hi > N_NODES) hi = N_NODES;
    int s = 0;
    for (int i = lo; i < hi; ++i) s += counts[i];
    partial[t] = s;
    __syncthreads();
    // Hillis-Steele inclusive scan
    for (int off = 1; off < T; off <<= 1) {
        int v = (t >= off) ? partial[t - off] : 0;
        __syncthreads();
        partial[t] += v;
        __syncthreads();
    }
    int run = (t == 0) ? 0 : partial[t - 1];
    for (int i = lo; i < hi; ++i) {
        int c = counts[i];
        offsets[i] = run;
        cursors[i] = run;
        dinv[i] = rsqrtf((float)c + 1.0f);  // +1 = self loop; deg >= 1 always
        run += c;
    }
    if (t == T - 1) offsets[N_NODES] = run;
}

__global__ void scatter_kernel(const int* __restrict__ src, const int* __restrict__ dst,
                               int* __restrict__ cursors, int* __restrict__ srcs) {
    int i = blockIdx.x * blockDim.x + threadIdx.x;
    int stride = gridDim.x * blockDim.x;
    for (int e = i; e < N_EDGES; e += stride) {
        int d = dst[e];
        int p = atomicAdd(&cursors[d], 1);
        srcs[p] = src[e];
    }
}

// hs[row][c] = dinv[row] * sum_k x[row][k] * W1[k][c]   (stored bf16)
// One wave per row; lane = output column; x row broadcast via __shfl.
__global__ __launch_bounds__(256) void gemm1_kernel(const float* __restrict__ x,
                                                    const float* __restrict__ W1,
                                                    const float* __restrict__ dinv,
                                                    __hip_bfloat16* __restrict__ hs) {
    __shared__ float W1s[D_IN * D_H];  // 32 KB
    for (int i = threadIdx.x; i < D_IN * D_H; i += 256) W1s[i] = W1[i];
    __syncthreads();
    int wave = threadIdx.x >> 6;
    int lane = threadIdx.x & 63;
    int waveStride = gridDim.x * 4;
    for (int row = blockIdx.x * 4 + wave; row < N_NODES; row += waveStride) {
        float2 xv = ((const float2*)x)[row * 64 + lane];  // x[row][2*lane .. 2*lane+1]
        float acc = 0.f;
        #pragma unroll
        for (int dd = 0; dd < 64; ++dd) {
            float a = __shfl(xv.x, dd);
            float b = __shfl(xv.y, dd);
            acc += a * W1s[(2 * dd) * D_H + lane];
            acc += b * W1s[(2 * dd + 1) * D_H + lane];
        }
        hs[row * D_H + lane] = __float2bfloat16(acc * dinv[row]);
    }
}

// relu_buf[i][c] = relu(dinv[i]*(hs[i][c] + sum_{j->i} hs[j][c]) + b1[c])
// One wave per node, lane = feature.
__global__ __launch_bounds__(256) void agg1_kernel(const __hip_bfloat16* __restrict__ hs,
                                                   const int* __restrict__ offsets,
                                                   const int* __restrict__ srcs,
                                                   const float* __restrict__ dinv,
                                                   const float* __restrict__ b1,
                                                   float* __restrict__ relu_buf) {
    int wave = (blockIdx.x * blockDim.x + threadIdx.x) >> 6;
    int lane = threadIdx.x & 63;
    int nwaves = (gridDim.x * blockDim.x) >> 6;
    for (int node = wave; node < N_NODES; node += nwaves) {
        int beg = offsets[node], end = offsets[node + 1];
        float acc = __bfloat162float(hs[node * D_H + lane]);  // self loop
        for (int e = beg; e < end; ++e) {
            int j = srcs[e];
            acc += __bfloat162float(hs[j * D_H + lane]);
        }
        float v = acc * dinv[node] + b1[lane];
        relu_buf[node * D_H + lane] = fmaxf(v, 0.f);
    }
}

// h2s[i][c] = dinv[i] * sum_d relu_buf[i][d] * W2[d][c]
// 16 threads per node (one per output col).
__global__ __launch_bounds__(256) void gemm2_kernel(const float* __restrict__ relu_buf,
                                                    const float* __restrict__ W2,
                                                    const float* __restrict__ dinv,
                                                    float* __restrict__ h2s) {
    __shared__ float W2s[D_H * D_OUT];  // 4 KB
    for (int i = threadIdx.x; i < D_H * D_OUT; i += 256) W2s[i] = W2[i];
    __syncthreads();
    int col = threadIdx.x & 15;
    int nidx = (blockIdx.x * blockDim.x + threadIdx.x) >> 4;
    int stride = (gridDim.x * blockDim.x) >> 4;
    for (int node = nidx; node < N_NODES; node += stride) {
        const float4* r4 = (const float4*)(relu_buf + node * D_H);
        float acc = 0.f;
        #pragma unroll
        for (int q = 0; q < 16; ++q) {
            float4 rv = r4[q];
            acc += rv.x * W2s[(4 * q + 0) * D_OUT + col];
            acc += rv.y * W2s[(4 * q + 1) * D_OUT + col];
            acc += rv.z * W2s[(4 * q + 2) * D_OUT + col];
            acc += rv.w * W2s[(4 * q + 3) * D_OUT + col];
        }
        h2s[node * D_OUT + col] = acc * dinv[node];
    }
}

// out[i][c] = dinv[i]*(h2s[i][c] + sum_{j->i} h2s[j][c]) + b2[c]
__global__ __launch_bounds__(256) void agg2_kernel(const float* __restrict__ h2s,
                                                   const int* __restrict__ offsets,
                                                   const int* __restrict__ srcs,
                                                   const float* __restrict__ dinv,
                                                   const float* __restrict__ b2,
                                                   float* __restrict__ out) {
    int col = threadIdx.x & 15;
    int nidx = (blockIdx.x * blockDim.x + threadIdx.x) >> 4;
    int stride = (gridDim.x * blockDim.x) >> 4;
    for (int node = nidx; node < N_NODES; node += stride) {
        int beg = offsets[node], end = offsets[node + 1];
        float acc = h2s[node * D_OUT + col];  // self loop
        for (int e = beg; e < end; ++e) {
            int j = srcs[e];
            acc += h2s[j * D_OUT + col];
        }
        out[node * D_OUT + col] = acc * dinv[node] + b2[col];
    }
}

extern "C" void kernel_launch(void* const* d_in, const int* in_sizes, int n_in,
                              void* d_out, int out_size, void* d_ws, size_t ws_size,
                              hipStream_t stream) {
    const float* x  = (const float*)d_in[0];
    const int*   ei = (const int*)d_in[1];
    const float* W1 = (const float*)d_in[2];
    const float* b1 = (const float*)d_in[3];
    const float* W2 = (const float*)d_in[4];
    const float* b2 = (const float*)d_in[5];
    float* out = (float*)d_out;

    const int* src = ei;             // edge_index[0]
    const int* dst = ei + N_EDGES;   // edge_index[1]

    char* w = (char*)d_ws;
    int*   counts   = (int*)(w + 0);
    int*   offsets  = (int*)(w + 400128);
    int*   cursors  = (int*)(w + 800256);
    float* dinv     = (float*)(w + 1200256);
    int*   srcs     = (int*)(w + 1600256);
    __hip_bfloat16* hs = (__hip_bfloat16*)(w + 8000256);
    float* relu_buf = (float*)(w + 20800256);
    float* h2s      = (float*)(w + 46400256);

    zero_kernel<<<(N_NODES + 255) / 256, 256, 0, stream>>>(counts, N_NODES);
    hist_kernel<<<2048, 256, 0, stream>>>(dst, counts);
    scan_kernel<<<1, 1024, 0, stream>>>(counts, offsets, cursors, dinv);
    scatter_kernel<<<2048, 256, 0, stream>>>(src, dst, cursors, srcs);
    gemm1_kernel<<<1024, 256, 0, stream>>>(x, W1, dinv, hs);
    agg1_kernel<<<6250, 256, 0, stream>>>(hs, offsets, srcs, dinv, b1, relu_buf);
    gemm2_kernel<<<6250, 256, 0, stream>>>(relu_buf, W2, dinv, h2s);
    agg2_kernel<<<6250, 256, 0, stream>>>(h2s, offsets, srcs, dinv, b2, out);
}

// Round 2
// 665.142 us; speedup vs baseline: 1.3951x; 1.3951x over previous
//
#include <hip/hip_runtime.h>
#include <hip/hip_bf16.h>
#include <cstdint>

// Problem constants (from reference)
#define N_NODES 100000
#define N_EDGES 1600000
#define D_IN    128
#define D_H     64
#define D_OUT   16
#define NB_SCAN 391   // ceil(N_NODES/256)

// ---------------------------------------------------------------------------
// Workspace layout (bytes, 128-aligned):
//   counts   : N int32            @ 0          (400000)
//   offsets  : N+1 int32          @ 400128     (400004)
//   cursors  : N int32            @ 800256     (400000)
//   dinv     : N float            @ 1200256    (400000)
//   srcs     : E int32 (CSR)      @ 1600256    (6400000)
//   hs       : N*64 bf16          @ 8000256    (12800000)
//   relu_buf : N*64 float         @ 20800256   (25600000)
//   h2s      : N*16 float         @ 46400256   (6400000)
//   bsums    : NB_SCAN int32      @ 52800256   (1564)
// total ~52.9 MB
// ---------------------------------------------------------------------------

__global__ void zero_kernel(int* __restrict__ p, int n) {
    int i = blockIdx.x * 256 + threadIdx.x;
    if (i < n) p[i] = 0;
}

__global__ void hist_kernel(const int* __restrict__ dst, int* __restrict__ counts) {
    int i = blockIdx.x * blockDim.x + threadIdx.x;
    int stride = gridDim.x * blockDim.x;
    for (int e = i; e < N_EDGES; e += stride)
        atomicAdd(&counts[dst[e]], 1);
}

// Phase A: per-block reduction of counts -> bsums[block]
__global__ __launch_bounds__(256) void blocksum_kernel(const int* __restrict__ counts,
                                                       int* __restrict__ bsums) {
    int gid = blockIdx.x * 256 + threadIdx.x;
    int c = (gid < N_NODES) ? counts[gid] : 0;
    int lane = threadIdx.x & 63;
    int wid = threadIdx.x >> 6;
    #pragma unroll
    for (int off = 32; off > 0; off >>= 1) c += __shfl_down(c, off);
    __shared__ int ws[4];
    if (lane == 0) ws[wid] = c;
    __syncthreads();
    if (threadIdx.x == 0) bsums[blockIdx.x] = ws[0] + ws[1] + ws[2] + ws[3];
}

// Phase B: single-block exclusive scan of bsums (NB_SCAN <= 512)
__global__ __launch_bounds__(512) void scan_bsums_kernel(int* __restrict__ bsums) {
    __shared__ int buf[512];
    int t = threadIdx.x;
    int v = (t < NB_SCAN) ? bsums[t] : 0;
    buf[t] = v;
    __syncthreads();
    for (int off = 1; off < 512; off <<= 1) {
        int u = (t >= off) ? buf[t - off] : 0;
        __syncthreads();
        buf[t] += u;
        __syncthreads();
    }
    if (t < NB_SCAN) bsums[t] = (t == 0) ? 0 : buf[t - 1];
}

// Phase C: block-level exclusive scan + block base -> offsets/cursors/dinv
__global__ __launch_bounds__(256) void scan_apply_kernel(const int* __restrict__ counts,
                                                         const int* __restrict__ bsums,
                                                         int* __restrict__ offsets,
                                                         int* __restrict__ cursors,
                                                         float* __restrict__ dinv) {
    int gid = blockIdx.x * 256 + threadIdx.x;
    int c = (gid < N_NODES) ? counts[gid] : 0;
    int lane = threadIdx.x & 63;
    int wid = threadIdx.x >> 6;
    // inclusive wave scan
    int v = c;
    #pragma unroll
    for (int off = 1; off < 64; off <<= 1) {
        int u = __shfl_up(v, off);
        if (lane >= off) v += u;
    }
    __shared__ int wsum[4];
    if (lane == 63) wsum[wid] = v;
    __syncthreads();
    int wadd = 0;
    for (int i = 0; i < wid; ++i) wadd += wsum[i];
    int incl = v + wadd;
    int base = bsums[blockIdx.x];
    if (gid < N_NODES) {
        int excl = base + incl - c;
        offsets[gid] = excl;
        cursors[gid] = excl;
        dinv[gid] = rsqrtf((float)c + 1.0f);  // +1 self loop; deg >= 1 always
        if (gid == N_NODES - 1) offsets[N_NODES] = base + incl;
    }
}

__global__ void scatter_kernel(const int* __restrict__ src, const int* __restrict__ dst,
                               int* __restrict__ cursors, int* __restrict__ srcs) {
    int i = blockIdx.x * blockDim.x + threadIdx.x;
    int stride = gridDim.x * blockDim.x;
    for (int e = i; e < N_EDGES; e += stride) {
        int d = dst[e];
        int p = atomicAdd(&cursors[d], 1);
        srcs[p] = src[e];
    }
}

// hs[row][c] = dinv[row] * sum_k x[row][k] * W1[k][c]   (stored bf16)
// One wave per row; lane = output column; x row broadcast via __shfl.
__global__ __launch_bounds__(256) void gemm1_kernel(const float* __restrict__ x,
                                                    const float* __restrict__ W1,
                                                    const float* __restrict__ dinv,
                                                    __hip_bfloat16* __restrict__ hs) {
    __shared__ float W1s[D_IN * D_H];  // 32 KB
    for (int i = threadIdx.x; i < D_IN * D_H; i += 256) W1s[i] = W1[i];
    __syncthreads();
    int wave = threadIdx.x >> 6;
    int lane = threadIdx.x & 63;
    int waveStride = gridDim.x * 4;
    for (int row = blockIdx.x * 4 + wave; row < N_NODES; row += waveStride) {
        float2 xv = ((const float2*)x)[row * 64 + lane];  // x[row][2*lane .. 2*lane+1]
        float acc = 0.f;
        #pragma unroll
        for (int dd = 0; dd < 64; ++dd) {
            float a = __shfl(xv.x, dd);
            float b = __shfl(xv.y, dd);
            acc += a * W1s[(2 * dd) * D_H + lane];
            acc += b * W1s[(2 * dd + 1) * D_H + lane];
        }
        hs[row * D_H + lane] = __float2bfloat16(acc * dinv[row]);
    }
}

// relu_buf[i][c] = relu(dinv[i]*(hs[i][c] + sum_{j->i} hs[j][c]) + b1[c])
// One wave per node, lane = feature.
__global__ __launch_bounds__(256) void agg1_kernel(const __hip_bfloat16* __restrict__ hs,
                                                   const int* __restrict__ offsets,
                                                   const int* __restrict__ srcs,
                                                   const float* __restrict__ dinv,
                                                   const float* __restrict__ b1,
                                                   float* __restrict__ relu_buf) {
    int wave = (blockIdx.x * blockDim.x + threadIdx.x) >> 6;
    int lane = threadIdx.x & 63;
    int nwaves = (gridDim.x * blockDim.x) >> 6;
    for (int node = wave; node < N_NODES; node += nwaves) {
        int beg = offsets[node], end = offsets[node + 1];
        float acc = __bfloat162float(hs[node * D_H + lane]);  // self loop
        for (int e = beg; e < end; ++e) {
            int j = srcs[e];
            acc += __bfloat162float(hs[j * D_H + lane]);
        }
        float v = acc * dinv[node] + b1[lane];
        relu_buf[node * D_H + lane] = fmaxf(v, 0.f);
    }
}

// h2s[i][c] = dinv[i] * sum_d relu_buf[i][d] * W2[d][c]
// 16 threads per node (one per output col).
__global__ __launch_bounds__(256) void gemm2_kernel(const float* __restrict__ relu_buf,
                                                    const float* __restrict__ W2,
                                                    const float* __restrict__ dinv,
                                                    float* __restrict__ h2s) {
    __shared__ float W2s[D_H * D_OUT];  // 4 KB
    for (int i = threadIdx.x; i < D_H * D_OUT; i += 256) W2s[i] = W2[i];
    __syncthreads();
    int col = threadIdx.x & 15;
    int nidx = (blockIdx.x * blockDim.x + threadIdx.x) >> 4;
    int stride = (gridDim.x * blockDim.x) >> 4;
    for (int node = nidx; node < N_NODES; node += stride) {
        const float4* r4 = (const float4*)(relu_buf + node * D_H);
        float acc = 0.f;
        #pragma unroll
        for (int q = 0; q < 16; ++q) {
            float4 rv = r4[q];
            acc += rv.x * W2s[(4 * q + 0) * D_OUT + col];
            acc += rv.y * W2s[(4 * q + 1) * D_OUT + col];
            acc += rv.z * W2s[(4 * q + 2) * D_OUT + col];
            acc += rv.w * W2s[(4 * q + 3) * D_OUT + col];
        }
        h2s[node * D_OUT + col] = acc * dinv[node];
    }
}

// out[i][c] = dinv[i]*(h2s[i][c] + sum_{j->i} h2s[j][c]) + b2[c]
__global__ __launch_bounds__(256) void agg2_kernel(const float* __restrict__ h2s,
                                                   const int* __restrict__ offsets,
                                                   const int* __restrict__ srcs,
                                                   const float* __restrict__ dinv,
                                                   const float* __restrict__ b2,
                                                   float* __restrict__ out) {
    int col = threadIdx.x & 15;
    int nidx = (blockIdx.x * blockDim.x + threadIdx.x) >> 4;
    int stride = (gridDim.x * blockDim.x) >> 4;
    for (int node = nidx; node < N_NODES; node += stride) {
        int beg = offsets[node], end = offsets[node + 1];
        float acc = h2s[node * D_OUT + col];  // self loop
        for (int e = beg; e < end; ++e) {
            int j = srcs[e];
            acc += h2s[j * D_OUT + col];
        }
        out[node * D_OUT + col] = acc * dinv[node] + b2[col];
    }
}

extern "C" void kernel_launch(void* const* d_in, const int* in_sizes, int n_in,
                              void* d_out, int out_size, void* d_ws, size_t ws_size,
                              hipStream_t stream) {
    const float* x  = (const float*)d_in[0];
    const int*   ei = (const int*)d_in[1];
    const float* W1 = (const float*)d_in[2];
    const float* b1 = (const float*)d_in[3];
    const float* W2 = (const float*)d_in[4];
    const float* b2 = (const float*)d_in[5];
    float* out = (float*)d_out;

    const int* src = ei;             // edge_index[0]
    const int* dst = ei + N_EDGES;   // edge_index[1]

    char* w = (char*)d_ws;
    int*   counts   = (int*)(w + 0);
    int*   offsets  = (int*)(w + 400128);
    int*   cursors  = (int*)(w + 800256);
    float* dinv     = (float*)(w + 1200256);
    int*   srcs     = (int*)(w + 1600256);
    __hip_bfloat16* hs = (__hip_bfloat16*)(w + 8000256);
    float* relu_buf = (float*)(w + 20800256);
    float* h2s      = (float*)(w + 46400256);
    int*   bsums    = (int*)(w + 52800256);

    zero_kernel<<<(N_NODES + 255) / 256, 256, 0, stream>>>(counts, N_NODES);
    hist_kernel<<<2048, 256, 0, stream>>>(dst, counts);
    blocksum_kernel<<<NB_SCAN, 256, 0, stream>>>(counts, bsums);
    scan_bsums_kernel<<<1, 512, 0, stream>>>(bsums);
    scan_apply_kernel<<<NB_SCAN, 256, 0, stream>>>(counts, bsums, offsets, cursors, dinv);
    scatter_kernel<<<2048, 256, 0, stream>>>(src, dst, cursors, srcs);
    gemm1_kernel<<<1024, 256, 0, stream>>>(x, W1, dinv, hs);
    agg1_kernel<<<6250, 256, 0, stream>>>(hs, offsets, srcs, dinv, b1, relu_buf);
    gemm2_kernel<<<6250, 256, 0, stream>>>(relu_buf, W2, dinv, h2s);
    agg2_kernel<<<6250, 256, 0, stream>>>(h2s, offsets, srcs, dinv, b2, out);
}

// Round 3
// 532.774 us; speedup vs baseline: 1.7418x; 1.2485x over previous
//
#include <hip/hip_runtime.h>
#include <cstdint>

// Problem constants (from reference)
#define N_NODES 100000
#define N_EDGES 1600000
#define D_IN    128
#define D_H     64
#define D_OUT   16
#define NB_SCAN 391   // ceil(N_NODES/256)
#define M_TILES 6250  // N_NODES / 16

typedef __attribute__((ext_vector_type(8))) short short8;
typedef __attribute__((ext_vector_type(4))) float floatx4;

// float -> bf16 bits (round to nearest even)
static __device__ __forceinline__ unsigned short f2bf(float f) {
    unsigned int u = __float_as_uint(f);
    u = u + 0x7FFFu + ((u >> 16) & 1u);
    return (unsigned short)(u >> 16);
}
static __device__ __forceinline__ float bf2f(unsigned short h) {
    return __uint_as_float(((unsigned int)h) << 16);
}

// ---------------------------------------------------------------------------
// Workspace layout (bytes, 128-aligned):
//   counts   : N int32            @ 0          (400000)
//   offsets  : N+1 int32          @ 400128     (400004)
//   cursors  : N int32            @ 800256     (400000)
//   dinv     : N float            @ 1200256    (400000)
//   srcs     : E int32 (CSR)      @ 1600256    (6400000)
//   hs       : N*64 bf16 bits     @ 8000256    (12800000)
//   relu_buf : N*64 float         @ 20800256   (25600000)
//   h2s      : N*16 float         @ 46400256   (6400000)
//   bsums    : NB_SCAN int32      @ 52800256   (1564)
// total ~52.9 MB
// ---------------------------------------------------------------------------

__global__ void zero_kernel(int* __restrict__ p, int n) {
    int i = blockIdx.x * 256 + threadIdx.x;
    if (i < n) p[i] = 0;
}

__global__ void hist_kernel(const int* __restrict__ dst, int* __restrict__ counts) {
    int i = blockIdx.x * blockDim.x + threadIdx.x;
    int stride = gridDim.x * blockDim.x;
    for (int e = i; e < N_EDGES; e += stride)
        atomicAdd(&counts[dst[e]], 1);
}

// Phase A: per-block reduction of counts -> bsums[block]
__global__ __launch_bounds__(256) void blocksum_kernel(const int* __restrict__ counts,
                                                       int* __restrict__ bsums) {
    int gid = blockIdx.x * 256 + threadIdx.x;
    int c = (gid < N_NODES) ? counts[gid] : 0;
    int lane = threadIdx.x & 63;
    int wid = threadIdx.x >> 6;
    #pragma unroll
    for (int off = 32; off > 0; off >>= 1) c += __shfl_down(c, off);
    __shared__ int ws[4];
    if (lane == 0) ws[wid] = c;
    __syncthreads();
    if (threadIdx.x == 0) bsums[blockIdx.x] = ws[0] + ws[1] + ws[2] + ws[3];
}

// Phase B: single-block exclusive scan of bsums (NB_SCAN <= 512)
__global__ __launch_bounds__(512) void scan_bsums_kernel(int* __restrict__ bsums) {
    __shared__ int buf[512];
    int t = threadIdx.x;
    int v = (t < NB_SCAN) ? bsums[t] : 0;
    buf[t] = v;
    __syncthreads();
    for (int off = 1; off < 512; off <<= 1) {
        int u = (t >= off) ? buf[t - off] : 0;
        __syncthreads();
        buf[t] += u;
        __syncthreads();
    }
    if (t < NB_SCAN) bsums[t] = (t == 0) ? 0 : buf[t - 1];
}

// Phase C: block-level exclusive scan + block base -> offsets/cursors/dinv
__global__ __launch_bounds__(256) void scan_apply_kernel(const int* __restrict__ counts,
                                                         const int* __restrict__ bsums,
                                                         int* __restrict__ offsets,
                                                         int* __restrict__ cursors,
                                                         float* __restrict__ dinv) {
    int gid = blockIdx.x * 256 + threadIdx.x;
    int c = (gid < N_NODES) ? counts[gid] : 0;
    int lane = threadIdx.x & 63;
    int wid = threadIdx.x >> 6;
    int v = c;
    #pragma unroll
    for (int off = 1; off < 64; off <<= 1) {
        int u = __shfl_up(v, off);
        if (lane >= off) v += u;
    }
    __shared__ int wsum[4];
    if (lane == 63) wsum[wid] = v;
    __syncthreads();
    int wadd = 0;
    for (int i = 0; i < wid; ++i) wadd += wsum[i];
    int incl = v + wadd;
    int base = bsums[blockIdx.x];
    if (gid < N_NODES) {
        int excl = base + incl - c;
        offsets[gid] = excl;
        cursors[gid] = excl;
        dinv[gid] = rsqrtf((float)c + 1.0f);  // +1 self loop; deg >= 1 always
        if (gid == N_NODES - 1) offsets[N_NODES] = base + incl;
    }
}

__global__ void scatter_kernel(const int* __restrict__ src, const int* __restrict__ dst,
                               int* __restrict__ cursors, int* __restrict__ srcs) {
    int i = blockIdx.x * blockDim.x + threadIdx.x;
    int stride = gridDim.x * blockDim.x;
    for (int e = i; e < N_EDGES; e += stride) {
        int d = dst[e];
        int p = atomicAdd(&cursors[d], 1);
        srcs[p] = src[e];
    }
}

// ---------------------------------------------------------------------------
// gemm1 via MFMA bf16x2 split precision:
//   hs[row][c] = bf16( dinv[row] * sum_k x[row][k] * W1[k][c] )
// Per wave: one 16-row M-tile, all 64 cols (4 n-tiles), K=128 (4 k-chunks).
// x and W1 are split x = hi + lo (bf16 each); product = hi*hi + hi*lo + lo*hi
// (lo*lo dropped, ~2^-18 relative). W1 fragments pre-staged in LDS per block.
// MFMA layouts (verified, guide §3/m120): A[m=lane&15][k=quad*8+j],
// B[n=lane&15][k=quad*8+j], C/D col=lane&15 row=quad*4+reg.
// ---------------------------------------------------------------------------
__global__ __launch_bounds__(256) void gemm1_mfma_kernel(const float* __restrict__ x,
                                                         const float* __restrict__ W1,
                                                         const float* __restrict__ dinv,
                                                         unsigned short* __restrict__ hs) {
    __shared__ unsigned short bhi_lds[8192];  // [ (kc*4+nt)*64 + lane ][8]
    __shared__ unsigned short blo_lds[8192];

    // --- stage W1 hi/lo fragments into LDS (8192 elements, 32 per thread) ---
    for (int e = threadIdx.x; e < 8192; e += 256) {
        int j    = e & 7;
        int lane = (e >> 3) & 63;
        int pair = e >> 9;          // 0..15 = kc*4 + nt
        int kc   = pair >> 2;
        int nt   = pair & 3;
        int k = kc * 32 + (lane >> 4) * 8 + j;
        int n = nt * 16 + (lane & 15);
        float w = W1[k * D_H + n];
        unsigned short hi = f2bf(w);
        float lo = w - bf2f(hi);
        bhi_lds[e] = hi;
        blo_lds[e] = f2bf(lo);
    }
    __syncthreads();

    int wid  = threadIdx.x >> 6;
    int lane = threadIdx.x & 63;
    int quad = lane >> 4;
    int m    = lane & 15;

    int tile = blockIdx.x * 4 + wid;
    if (tile >= M_TILES) return;
    int mbase = tile * 16;

    // --- load + split A fragments ---
    const float* xr = x + (size_t)(mbase + m) * D_IN + quad * 8;
    short8 ahi[4], alo[4];
    #pragma unroll
    for (int kc = 0; kc < 4; ++kc) {
        floatx4 v0 = *(const floatx4*)(xr + kc * 32);
        floatx4 v1 = *(const floatx4*)(xr + kc * 32 + 4);
        float f[8] = {v0.x, v0.y, v0.z, v0.w, v1.x, v1.y, v1.z, v1.w};
        #pragma unroll
        for (int j = 0; j < 8; ++j) {
            unsigned short hi = f2bf(f[j]);
            float lo = f[j] - bf2f(hi);
            ahi[kc][j] = (short)hi;
            alo[kc][j] = (short)f2bf(lo);
        }
    }

    // --- MFMA accumulate ---
    floatx4 acc[4] = {{0.f,0.f,0.f,0.f},{0.f,0.f,0.f,0.f},{0.f,0.f,0.f,0.f},{0.f,0.f,0.f,0.f}};
    #pragma unroll
    for (int kc = 0; kc < 4; ++kc) {
        #pragma unroll
        for (int nt = 0; nt < 4; ++nt) {
            int fo = ((kc * 4 + nt) * 64 + lane) * 8;
            short8 bhi = *(const short8*)&bhi_lds[fo];
            short8 blo = *(const short8*)&blo_lds[fo];
            acc[nt] = __builtin_amdgcn_mfma_f32_16x16x32_bf16(ahi[kc], bhi, acc[nt], 0, 0, 0);
            acc[nt] = __builtin_amdgcn_mfma_f32_16x16x32_bf16(ahi[kc], blo, acc[nt], 0, 0, 0);
            acc[nt] = __builtin_amdgcn_mfma_f32_16x16x32_bf16(alo[kc], bhi, acc[nt], 0, 0, 0);
        }
    }

    // --- epilogue: scale by dinv, store bf16 ---
    float dv[4];
    #pragma unroll
    for (int r = 0; r < 4; ++r) dv[r] = dinv[mbase + quad * 4 + r];
    #pragma unroll
    for (int nt = 0; nt < 4; ++nt) {
        int col = nt * 16 + m;
        #pragma unroll
        for (int r = 0; r < 4; ++r) {
            int row = mbase + quad * 4 + r;
            hs[row * D_H + col] = f2bf(acc[nt][r] * dv[r]);
        }
    }
}

// relu_buf[i][c] = relu(dinv[i]*(hs[i][c] + sum_{j->i} hs[j][c]) + b1[c])
// One wave per node, lane = feature.
__global__ __launch_bounds__(256) void agg1_kernel(const unsigned short* __restrict__ hs,
                                                   const int* __restrict__ offsets,
                                                   const int* __restrict__ srcs,
                                                   const float* __restrict__ dinv,
                                                   const float* __restrict__ b1,
                                                   float* __restrict__ relu_buf) {
    int wave = (blockIdx.x * blockDim.x + threadIdx.x) >> 6;
    int lane = threadIdx.x & 63;
    int nwaves = (gridDim.x * blockDim.x) >> 6;
    for (int node = wave; node < N_NODES; node += nwaves) {
        int beg = offsets[node], end = offsets[node + 1];
        float acc = bf2f(hs[node * D_H + lane]);  // self loop
        for (int e = beg; e < end; ++e) {
            int j = srcs[e];
            acc += bf2f(hs[j * D_H + lane]);
        }
        float v = acc * dinv[node] + b1[lane];
        relu_buf[node * D_H + lane] = fmaxf(v, 0.f);
    }
}

// h2s[i][c] = dinv[i] * sum_d relu_buf[i][d] * W2[d][c]
__global__ __launch_bounds__(256) void gemm2_kernel(const float* __restrict__ relu_buf,
                                                    const float* __restrict__ W2,
                                                    const float* __restrict__ dinv,
                                                    float* __restrict__ h2s) {
    __shared__ float W2s[D_H * D_OUT];  // 4 KB
    for (int i = threadIdx.x; i < D_H * D_OUT; i += 256) W2s[i] = W2[i];
    __syncthreads();
    int col = threadIdx.x & 15;
    int nidx = (blockIdx.x * blockDim.x + threadIdx.x) >> 4;
    int stride = (gridDim.x * blockDim.x) >> 4;
    for (int node = nidx; node < N_NODES; node += stride) {
        const float4* r4 = (const float4*)(relu_buf + node * D_H);
        float acc = 0.f;
        #pragma unroll
        for (int q = 0; q < 16; ++q) {
            float4 rv = r4[q];
            acc += rv.x * W2s[(4 * q + 0) * D_OUT + col];
            acc += rv.y * W2s[(4 * q + 1) * D_OUT + col];
            acc += rv.z * W2s[(4 * q + 2) * D_OUT + col];
            acc += rv.w * W2s[(4 * q + 3) * D_OUT + col];
        }
        h2s[node * D_OUT + col] = acc * dinv[node];
    }
}

// out[i][c] = dinv[i]*(h2s[i][c] + sum_{j->i} h2s[j][c]) + b2[c]
__global__ __launch_bounds__(256) void agg2_kernel(const float* __restrict__ h2s,
                                                   const int* __restrict__ offsets,
                                                   const int* __restrict__ srcs,
                                                   const float* __restrict__ dinv,
                                                   const float* __restrict__ b2,
                                                   float* __restrict__ out) {
    int col = threadIdx.x & 15;
    int nidx = (blockIdx.x * blockDim.x + threadIdx.x) >> 4;
    int stride = (gridDim.x * blockDim.x) >> 4;
    for (int node = nidx; node < N_NODES; node += stride) {
        int beg = offsets[node], end = offsets[node + 1];
        float acc = h2s[node * D_OUT + col];  // self loop
        for (int e = beg; e < end; ++e) {
            int j = srcs[e];
            acc += h2s[j * D_OUT + col];
        }
        out[node * D_OUT + col] = acc * dinv[node] + b2[col];
    }
}

extern "C" void kernel_launch(void* const* d_in, const int* in_sizes, int n_in,
                              void* d_out, int out_size, void* d_ws, size_t ws_size,
                              hipStream_t stream) {
    const float* x  = (const float*)d_in[0];
    const int*   ei = (const int*)d_in[1];
    const float* W1 = (const float*)d_in[2];
    const float* b1 = (const float*)d_in[3];
    const float* W2 = (const float*)d_in[4];
    const float* b2 = (const float*)d_in[5];
    float* out = (float*)d_out;

    const int* src = ei;             // edge_index[0]
    const int* dst = ei + N_EDGES;   // edge_index[1]

    char* w = (char*)d_ws;
    int*   counts   = (int*)(w + 0);
    int*   offsets  = (int*)(w + 400128);
    int*   cursors  = (int*)(w + 800256);
    float* dinv     = (float*)(w + 1200256);
    int*   srcs     = (int*)(w + 1600256);
    unsigned short* hs = (unsigned short*)(w + 8000256);
    float* relu_buf = (float*)(w + 20800256);
    float* h2s      = (float*)(w + 46400256);
    int*   bsums    = (int*)(w + 52800256);

    zero_kernel<<<(N_NODES + 255) / 256, 256, 0, stream>>>(counts, N_NODES);
    hist_kernel<<<2048, 256, 0, stream>>>(dst, counts);
    blocksum_kernel<<<NB_SCAN, 256, 0, stream>>>(counts, bsums);
    scan_bsums_kernel<<<1, 512, 0, stream>>>(bsums);
    scan_apply_kernel<<<NB_SCAN, 256, 0, stream>>>(counts, bsums, offsets, cursors, dinv);
    scatter_kernel<<<2048, 256, 0, stream>>>(src, dst, cursors, srcs);
    gemm1_mfma_kernel<<<(M_TILES + 3) / 4, 256, 0, stream>>>(x, W1, dinv, hs);
    agg1_kernel<<<6250, 256, 0, stream>>>(hs, offsets, srcs, dinv, b1, relu_buf);
    gemm2_kernel<<<6250, 256, 0, stream>>>(relu_buf, W2, dinv, h2s);
    agg2_kernel<<<6250, 256, 0, stream>>>(h2s, offsets, srcs, dinv, b2, out);
}

// Round 4
// 439.869 us; speedup vs baseline: 2.1096x; 1.2112x over previous
//
#include <hip/hip_runtime.h>
#include <cstdint>

// Problem constants (from reference)
#define N_NODES 100000
#define N_EDGES 1600000
#define D_IN    128
#define D_H     64
#define D_OUT   16
#define NB_SCAN 391   // ceil(N_NODES/256)
#define M_TILES 6250  // N_NODES / 16

typedef __attribute__((ext_vector_type(8))) short short8;
typedef __attribute__((ext_vector_type(4))) float floatx4;

// float -> bf16 bits (round to nearest even)
static __device__ __forceinline__ unsigned short f2bf(float f) {
    unsigned int u = __float_as_uint(f);
    u = u + 0x7FFFu + ((u >> 16) & 1u);
    return (unsigned short)(u >> 16);
}
static __device__ __forceinline__ float bf2f(unsigned short h) {
    return __uint_as_float(((unsigned int)h) << 16);
}

// ---------------------------------------------------------------------------
// Workspace layout (bytes, 128-aligned):
//   counts   : N int32            @ 0          (400000)
//   offsets  : N+1 int32          @ 400128     (400004)
//   cursors  : N int32            @ 800256     (400000)
//   dinv     : N float            @ 1200256    (400000)
//   srcs     : E int32 (CSR)      @ 1600256    (6400000)
//   hs       : N*64 bf16 bits     @ 8000256    (12800000)
//   relu_buf : N*64 float         @ 20800256   (25600000)
//   h2s      : N*16 float         @ 46400256   (6400000)
//   bsums    : NB_SCAN int32      @ 52800256   (1564)
// total ~52.9 MB
// ---------------------------------------------------------------------------

__global__ void zero_kernel(int* __restrict__ p, int n) {
    int i = blockIdx.x * 256 + threadIdx.x;
    if (i < n) p[i] = 0;
}

__global__ void hist_kernel(const int* __restrict__ dst, int* __restrict__ counts) {
    int i = blockIdx.x * blockDim.x + threadIdx.x;
    int stride = gridDim.x * blockDim.x;
    for (int e = i; e < N_EDGES; e += stride)
        atomicAdd(&counts[dst[e]], 1);
}

// Phase A: per-block reduction of counts -> bsums[block]
__global__ __launch_bounds__(256) void blocksum_kernel(const int* __restrict__ counts,
                                                       int* __restrict__ bsums) {
    int gid = blockIdx.x * 256 + threadIdx.x;
    int c = (gid < N_NODES) ? counts[gid] : 0;
    int lane = threadIdx.x & 63;
    int wid = threadIdx.x >> 6;
    #pragma unroll
    for (int off = 32; off > 0; off >>= 1) c += __shfl_down(c, off);
    __shared__ int ws[4];
    if (lane == 0) ws[wid] = c;
    __syncthreads();
    if (threadIdx.x == 0) bsums[blockIdx.x] = ws[0] + ws[1] + ws[2] + ws[3];
}

// Phase B: single-block exclusive scan of bsums (NB_SCAN <= 512)
__global__ __launch_bounds__(512) void scan_bsums_kernel(int* __restrict__ bsums) {
    __shared__ int buf[512];
    int t = threadIdx.x;
    int v = (t < NB_SCAN) ? bsums[t] : 0;
    buf[t] = v;
    __syncthreads();
    for (int off = 1; off < 512; off <<= 1) {
        int u = (t >= off) ? buf[t - off] : 0;
        __syncthreads();
        buf[t] += u;
        __syncthreads();
    }
    if (t < NB_SCAN) bsums[t] = (t == 0) ? 0 : buf[t - 1];
}

// Phase C: block-level exclusive scan + block base -> offsets/cursors/dinv
__global__ __launch_bounds__(256) void scan_apply_kernel(const int* __restrict__ counts,
                                                         const int* __restrict__ bsums,
                                                         int* __restrict__ offsets,
                                                         int* __restrict__ cursors,
                                                         float* __restrict__ dinv) {
    int gid = blockIdx.x * 256 + threadIdx.x;
    int c = (gid < N_NODES) ? counts[gid] : 0;
    int lane = threadIdx.x & 63;
    int wid = threadIdx.x >> 6;
    int v = c;
    #pragma unroll
    for (int off = 1; off < 64; off <<= 1) {
        int u = __shfl_up(v, off);
        if (lane >= off) v += u;
    }
    __shared__ int wsum[4];
    if (lane == 63) wsum[wid] = v;
    __syncthreads();
    int wadd = 0;
    for (int i = 0; i < wid; ++i) wadd += wsum[i];
    int incl = v + wadd;
    int base = bsums[blockIdx.x];
    if (gid < N_NODES) {
        int excl = base + incl - c;
        offsets[gid] = excl;
        cursors[gid] = excl;
        dinv[gid] = rsqrtf((float)c + 1.0f);  // +1 self loop; deg >= 1 always
        if (gid == N_NODES - 1) offsets[N_NODES] = base + incl;
    }
}

__global__ void scatter_kernel(const int* __restrict__ src, const int* __restrict__ dst,
                               int* __restrict__ cursors, int* __restrict__ srcs) {
    int i = blockIdx.x * blockDim.x + threadIdx.x;
    int stride = gridDim.x * blockDim.x;
    for (int e = i; e < N_EDGES; e += stride) {
        int d = dst[e];
        int p = atomicAdd(&cursors[d], 1);
        srcs[p] = src[e];
    }
}

// ---------------------------------------------------------------------------
// gemm1 via MFMA bf16x2 split precision (unchanged from R2, 166->~30us then).
// ---------------------------------------------------------------------------
__global__ __launch_bounds__(256) void gemm1_mfma_kernel(const float* __restrict__ x,
                                                         const float* __restrict__ W1,
                                                         const float* __restrict__ dinv,
                                                         unsigned short* __restrict__ hs) {
    __shared__ unsigned short bhi_lds[8192];  // [ (kc*4+nt)*64 + lane ][8]
    __shared__ unsigned short blo_lds[8192];

    for (int e = threadIdx.x; e < 8192; e += 256) {
        int j    = e & 7;
        int lane = (e >> 3) & 63;
        int pair = e >> 9;          // 0..15 = kc*4 + nt
        int kc   = pair >> 2;
        int nt   = pair & 3;
        int k = kc * 32 + (lane >> 4) * 8 + j;
        int n = nt * 16 + (lane & 15);
        float w = W1[k * D_H + n];
        unsigned short hi = f2bf(w);
        float lo = w - bf2f(hi);
        bhi_lds[e] = hi;
        blo_lds[e] = f2bf(lo);
    }
    __syncthreads();

    int wid  = threadIdx.x >> 6;
    int lane = threadIdx.x & 63;
    int quad = lane >> 4;
    int m    = lane & 15;

    int tile = blockIdx.x * 4 + wid;
    if (tile >= M_TILES) return;
    int mbase = tile * 16;

    const float* xr = x + (size_t)(mbase + m) * D_IN + quad * 8;
    short8 ahi[4], alo[4];
    #pragma unroll
    for (int kc = 0; kc < 4; ++kc) {
        floatx4 v0 = *(const floatx4*)(xr + kc * 32);
        floatx4 v1 = *(const floatx4*)(xr + kc * 32 + 4);
        float f[8] = {v0.x, v0.y, v0.z, v0.w, v1.x, v1.y, v1.z, v1.w};
        #pragma unroll
        for (int j = 0; j < 8; ++j) {
            unsigned short hi = f2bf(f[j]);
            float lo = f[j] - bf2f(hi);
            ahi[kc][j] = (short)hi;
            alo[kc][j] = (short)f2bf(lo);
        }
    }

    floatx4 acc[4] = {{0.f,0.f,0.f,0.f},{0.f,0.f,0.f,0.f},{0.f,0.f,0.f,0.f},{0.f,0.f,0.f,0.f}};
    #pragma unroll
    for (int kc = 0; kc < 4; ++kc) {
        #pragma unroll
        for (int nt = 0; nt < 4; ++nt) {
            int fo = ((kc * 4 + nt) * 64 + lane) * 8;
            short8 bhi = *(const short8*)&bhi_lds[fo];
            short8 blo = *(const short8*)&blo_lds[fo];
            acc[nt] = __builtin_amdgcn_mfma_f32_16x16x32_bf16(ahi[kc], bhi, acc[nt], 0, 0, 0);
            acc[nt] = __builtin_amdgcn_mfma_f32_16x16x32_bf16(ahi[kc], blo, acc[nt], 0, 0, 0);
            acc[nt] = __builtin_amdgcn_mfma_f32_16x16x32_bf16(alo[kc], bhi, acc[nt], 0, 0, 0);
        }
    }

    float dv[4];
    #pragma unroll
    for (int r = 0; r < 4; ++r) dv[r] = dinv[mbase + quad * 4 + r];
    #pragma unroll
    for (int nt = 0; nt < 4; ++nt) {
        int col = nt * 16 + m;
        #pragma unroll
        for (int r = 0; r < 4; ++r) {
            int row = mbase + quad * 4 + r;
            hs[row * D_H + col] = f2bf(acc[nt][r] * dv[r]);
        }
    }
}

// relu_buf[i][c] = relu(dinv[i]*(hs[i][c] + sum_{j->i} hs[j][c]) + b1[c])
// One wave per node, lane = feature. Edge loop unrolled x8 for MLP:
// 8 outstanding 128B gathers per wave instead of ~1.
__global__ __launch_bounds__(256) void agg1_kernel(const unsigned short* __restrict__ hs,
                                                   const int* __restrict__ offsets,
                                                   const int* __restrict__ srcs,
                                                   const float* __restrict__ dinv,
                                                   const float* __restrict__ b1,
                                                   float* __restrict__ relu_buf) {
    int wave = (blockIdx.x * blockDim.x + threadIdx.x) >> 6;
    int lane = threadIdx.x & 63;
    int nwaves = (gridDim.x * blockDim.x) >> 6;
    for (int node = wave; node < N_NODES; node += nwaves) {
        int beg = offsets[node], end = offsets[node + 1];
        float acc = bf2f(hs[node * D_H + lane]);  // self loop
        int e = beg;
        for (; e + 8 <= end; e += 8) {
            int j0 = srcs[e + 0], j1 = srcs[e + 1], j2 = srcs[e + 2], j3 = srcs[e + 3];
            int j4 = srcs[e + 4], j5 = srcs[e + 5], j6 = srcs[e + 6], j7 = srcs[e + 7];
            float v0 = bf2f(hs[j0 * D_H + lane]);
            float v1 = bf2f(hs[j1 * D_H + lane]);
            float v2 = bf2f(hs[j2 * D_H + lane]);
            float v3 = bf2f(hs[j3 * D_H + lane]);
            float v4 = bf2f(hs[j4 * D_H + lane]);
            float v5 = bf2f(hs[j5 * D_H + lane]);
            float v6 = bf2f(hs[j6 * D_H + lane]);
            float v7 = bf2f(hs[j7 * D_H + lane]);
            acc += ((v0 + v1) + (v2 + v3)) + ((v4 + v5) + (v6 + v7));
        }
        for (; e < end; ++e) {
            acc += bf2f(hs[srcs[e] * D_H + lane]);
        }
        float v = acc * dinv[node] + b1[lane];
        relu_buf[node * D_H + lane] = fmaxf(v, 0.f);
    }
}

// h2s[i][c] = dinv[i] * sum_d relu_buf[i][d] * W2[d][c]
__global__ __launch_bounds__(256) void gemm2_kernel(const float* __restrict__ relu_buf,
                                                    const float* __restrict__ W2,
                                                    const float* __restrict__ dinv,
                                                    float* __restrict__ h2s) {
    __shared__ float W2s[D_H * D_OUT];  // 4 KB
    for (int i = threadIdx.x; i < D_H * D_OUT; i += 256) W2s[i] = W2[i];
    __syncthreads();
    int col = threadIdx.x & 15;
    int nidx = (blockIdx.x * blockDim.x + threadIdx.x) >> 4;
    int stride = (gridDim.x * blockDim.x) >> 4;
    for (int node = nidx; node < N_NODES; node += stride) {
        const float4* r4 = (const float4*)(relu_buf + node * D_H);
        float acc = 0.f;
        #pragma unroll
        for (int q = 0; q < 16; ++q) {
            float4 rv = r4[q];
            acc += rv.x * W2s[(4 * q + 0) * D_OUT + col];
            acc += rv.y * W2s[(4 * q + 1) * D_OUT + col];
            acc += rv.z * W2s[(4 * q + 2) * D_OUT + col];
            acc += rv.w * W2s[(4 * q + 3) * D_OUT + col];
        }
        h2s[node * D_OUT + col] = acc * dinv[node];
    }
}

// out[i][c] = dinv[i]*(h2s[i][c] + sum_{j->i} h2s[j][c]) + b2[c]
// 16 threads per node; edge loop unrolled x8 (8 outstanding 64B gathers).
__global__ __launch_bounds__(256) void agg2_kernel(const float* __restrict__ h2s,
                                                   const int* __restrict__ offsets,
                                                   const int* __restrict__ srcs,
                                                   const float* __restrict__ dinv,
                                                   const float* __restrict__ b2,
                                                   float* __restrict__ out) {
    int col = threadIdx.x & 15;
    int nidx = (blockIdx.x * blockDim.x + threadIdx.x) >> 4;
    int stride = (gridDim.x * blockDim.x) >> 4;
    for (int node = nidx; node < N_NODES; node += stride) {
        int beg = offsets[node], end = offsets[node + 1];
        float acc = h2s[node * D_OUT + col];  // self loop
        int e = beg;
        for (; e + 8 <= end; e += 8) {
            int j0 = srcs[e + 0], j1 = srcs[e + 1], j2 = srcs[e + 2], j3 = srcs[e + 3];
            int j4 = srcs[e + 4], j5 = srcs[e + 5], j6 = srcs[e + 6], j7 = srcs[e + 7];
            float v0 = h2s[j0 * D_OUT + col];
            float v1 = h2s[j1 * D_OUT + col];
            float v2 = h2s[j2 * D_OUT + col];
            float v3 = h2s[j3 * D_OUT + col];
            float v4 = h2s[j4 * D_OUT + col];
            float v5 = h2s[j5 * D_OUT + col];
            float v6 = h2s[j6 * D_OUT + col];
            float v7 = h2s[j7 * D_OUT + col];
            acc += ((v0 + v1) + (v2 + v3)) + ((v4 + v5) + (v6 + v7));
        }
        for (; e < end; ++e) {
            acc += h2s[srcs[e] * D_OUT + col];
        }
        out[node * D_OUT + col] = acc * dinv[node] + b2[col];
    }
}

extern "C" void kernel_launch(void* const* d_in, const int* in_sizes, int n_in,
                              void* d_out, int out_size, void* d_ws, size_t ws_size,
                              hipStream_t stream) {
    const float* x  = (const float*)d_in[0];
    const int*   ei = (const int*)d_in[1];
    const float* W1 = (const float*)d_in[2];
    const float* b1 = (const float*)d_in[3];
    const float* W2 = (const float*)d_in[4];
    const float* b2 = (const float*)d_in[5];
    float* out = (float*)d_out;

    const int* src = ei;             // edge_index[0]
    const int* dst = ei + N_EDGES;   // edge_index[1]

    char* w = (char*)d_ws;
    int*   counts   = (int*)(w + 0);
    int*   offsets  = (int*)(w + 400128);
    int*   cursors  = (int*)(w + 800256);
    float* dinv     = (float*)(w + 1200256);
    int*   srcs     = (int*)(w + 1600256);
    unsigned short* hs = (unsigned short*)(w + 8000256);
    float* relu_buf = (float*)(w + 20800256);
    float* h2s      = (float*)(w + 46400256);
    int*   bsums    = (int*)(w + 52800256);

    zero_kernel<<<(N_NODES + 255) / 256, 256, 0, stream>>>(counts, N_NODES);
    hist_kernel<<<2048, 256, 0, stream>>>(dst, counts);
    blocksum_kernel<<<NB_SCAN, 256, 0, stream>>>(counts, bsums);
    scan_bsums_kernel<<<1, 512, 0, stream>>>(bsums);
    scan_apply_kernel<<<NB_SCAN, 256, 0, stream>>>(counts, bsums, offsets, cursors, dinv);
    scatter_kernel<<<2048, 256, 0, stream>>>(src, dst, cursors, srcs);
    gemm1_mfma_kernel<<<(M_TILES + 3) / 4, 256, 0, stream>>>(x, W1, dinv, hs);
    agg1_kernel<<<6250, 256, 0, stream>>>(hs, offsets, srcs, dinv, b1, relu_buf);
    gemm2_kernel<<<6250, 256, 0, stream>>>(relu_buf, W2, dinv, h2s);
    agg2_kernel<<<6250, 256, 0, stream>>>(h2s, offsets, srcs, dinv, b2, out);
}

// Round 5
// 380.430 us; speedup vs baseline: 2.4392x; 1.1562x over previous
//
#include <hip/hip_runtime.h>
#include <cstdint>

// Problem constants (from reference)
#define N_NODES 100000
#define N_EDGES 1600000
#define D_IN    128
#define D_H     64
#define D_OUT   16
#define NB_SCAN 391   // ceil(N_NODES/256)
#define M_TILES 6250  // N_NODES / 16
#define N_PART  8     // XCD count; dst-range partitions for scatter
#define PART_SZ 12500 // N_NODES / N_PART

typedef __attribute__((ext_vector_type(8))) short short8;
typedef __attribute__((ext_vector_type(4))) float floatx4;

// float -> bf16 bits (round to nearest even)
static __device__ __forceinline__ unsigned short f2bf(float f) {
    unsigned int u = __float_as_uint(f);
    u = u + 0x7FFFu + ((u >> 16) & 1u);
    return (unsigned short)(u >> 16);
}
static __device__ __forceinline__ float bf2f(unsigned short h) {
    return __uint_as_float(((unsigned int)h) << 16);
}

// ---------------------------------------------------------------------------
// Workspace layout (bytes, 128-aligned):
//   counts   : N int32            @ 0          (400000)
//   offsets  : N+1 int32          @ 400128     (400004)
//   cursors  : N int32            @ 800256     (400000)
//   dinv     : N float            @ 1200256    (400000)
//   srcs     : E int32 (CSR)      @ 1600256    (6400000)
//   hs       : N*64 bf16 bits     @ 8000256    (12800000)
//   relu_buf : N*64 float         @ 20800256   (25600000)
//   h2s      : N*16 float         @ 46400256   (6400000)
//   bsums    : NB_SCAN int32      @ 52800256   (1564)
// total ~52.9 MB
// ---------------------------------------------------------------------------

__global__ void zero_kernel(int* __restrict__ p, int n) {
    int i = blockIdx.x * 256 + threadIdx.x;
    if (i < n) p[i] = 0;
}

__global__ void hist_kernel(const int* __restrict__ dst, int* __restrict__ counts) {
    int i = blockIdx.x * blockDim.x + threadIdx.x;
    int stride = gridDim.x * blockDim.x;
    for (int e = i; e < N_EDGES; e += stride)
        atomicAdd(&counts[dst[e]], 1);
}

// Phase A: per-block reduction of counts -> bsums[block]
__global__ __launch_bounds__(256) void blocksum_kernel(const int* __restrict__ counts,
                                                       int* __restrict__ bsums) {
    int gid = blockIdx.x * 256 + threadIdx.x;
    int c = (gid < N_NODES) ? counts[gid] : 0;
    int lane = threadIdx.x & 63;
    int wid = threadIdx.x >> 6;
    #pragma unroll
    for (int off = 32; off > 0; off >>= 1) c += __shfl_down(c, off);
    __shared__ int ws[4];
    if (lane == 0) ws[wid] = c;
    __syncthreads();
    if (threadIdx.x == 0) bsums[blockIdx.x] = ws[0] + ws[1] + ws[2] + ws[3];
}

// Phase B: single-block exclusive scan of bsums (NB_SCAN <= 512)
__global__ __launch_bounds__(512) void scan_bsums_kernel(int* __restrict__ bsums) {
    __shared__ int buf[512];
    int t = threadIdx.x;
    int v = (t < NB_SCAN) ? bsums[t] : 0;
    buf[t] = v;
    __syncthreads();
    for (int off = 1; off < 512; off <<= 1) {
        int u = (t >= off) ? buf[t - off] : 0;
        __syncthreads();
        buf[t] += u;
        __syncthreads();
    }
    if (t < NB_SCAN) bsums[t] = (t == 0) ? 0 : buf[t - 1];
}

// Phase C: block-level exclusive scan + block base -> offsets/cursors/dinv
__global__ __launch_bounds__(256) void scan_apply_kernel(const int* __restrict__ counts,
                                                         const int* __restrict__ bsums,
                                                         int* __restrict__ offsets,
                                                         int* __restrict__ cursors,
                                                         float* __restrict__ dinv) {
    int gid = blockIdx.x * 256 + threadIdx.x;
    int c = (gid < N_NODES) ? counts[gid] : 0;
    int lane = threadIdx.x & 63;
    int wid = threadIdx.x >> 6;
    int v = c;
    #pragma unroll
    for (int off = 1; off < 64; off <<= 1) {
        int u = __shfl_up(v, off);
        if (lane >= off) v += u;
    }
    __shared__ int wsum[4];
    if (lane == 63) wsum[wid] = v;
    __syncthreads();
    int wadd = 0;
    for (int i = 0; i < wid; ++i) wadd += wsum[i];
    int incl = v + wadd;
    int base = bsums[blockIdx.x];
    if (gid < N_NODES) {
        int excl = base + incl - c;
        offsets[gid] = excl;
        cursors[gid] = excl;
        dinv[gid] = rsqrtf((float)c + 1.0f);  // +1 self loop; deg >= 1 always
        if (gid == N_NODES - 1) offsets[N_NODES] = base + incl;
    }
}

// XCD-partitioned CSR scatter: partition = blockIdx & 7 (round-robin XCD
// heuristic). All writes + cursor atomics for a dst range come from one
// XCD's L2 -> full-line writebacks instead of 16x partial-line amplification.
// Correctness does NOT depend on the XCD mapping, only speed.
__global__ __launch_bounds__(256) void scatter_kernel(const int* __restrict__ src,
                                                      const int* __restrict__ dst,
                                                      int* __restrict__ cursors,
                                                      int* __restrict__ srcs) {
    int part = blockIdx.x & (N_PART - 1);
    int lo = part * PART_SZ;
    int hi = lo + PART_SZ;
    int bi = blockIdx.x >> 3;            // block index within partition
    int nb = gridDim.x >> 3;             // blocks per partition
    int tid = bi * 256 + threadIdx.x;
    int stride = nb * 256;
    for (int e = tid; e < N_EDGES; e += stride) {
        int d = dst[e];
        if (d >= lo && d < hi) {
            int p = atomicAdd(&cursors[d], 1);
            srcs[p] = src[e];
        }
    }
}

// ---------------------------------------------------------------------------
// gemm1 via MFMA bf16x2 split precision.
// ---------------------------------------------------------------------------
__global__ __launch_bounds__(256) void gemm1_mfma_kernel(const float* __restrict__ x,
                                                         const float* __restrict__ W1,
                                                         const float* __restrict__ dinv,
                                                         unsigned short* __restrict__ hs) {
    __shared__ unsigned short bhi_lds[8192];  // [ (kc*4+nt)*64 + lane ][8]
    __shared__ unsigned short blo_lds[8192];

    for (int e = threadIdx.x; e < 8192; e += 256) {
        int j    = e & 7;
        int lane = (e >> 3) & 63;
        int pair = e >> 9;          // 0..15 = kc*4 + nt
        int kc   = pair >> 2;
        int nt   = pair & 3;
        int k = kc * 32 + (lane >> 4) * 8 + j;
        int n = nt * 16 + (lane & 15);
        float w = W1[k * D_H + n];
        unsigned short hi = f2bf(w);
        float lo = w - bf2f(hi);
        bhi_lds[e] = hi;
        blo_lds[e] = f2bf(lo);
    }
    __syncthreads();

    int wid  = threadIdx.x >> 6;
    int lane = threadIdx.x & 63;
    int quad = lane >> 4;
    int m    = lane & 15;

    int tile = blockIdx.x * 4 + wid;
    if (tile >= M_TILES) return;
    int mbase = tile * 16;

    const float* xr = x + (size_t)(mbase + m) * D_IN + quad * 8;
    short8 ahi[4], alo[4];
    #pragma unroll
    for (int kc = 0; kc < 4; ++kc) {
        floatx4 v0 = *(const floatx4*)(xr + kc * 32);
        floatx4 v1 = *(const floatx4*)(xr + kc * 32 + 4);
        float f[8] = {v0.x, v0.y, v0.z, v0.w, v1.x, v1.y, v1.z, v1.w};
        #pragma unroll
        for (int j = 0; j < 8; ++j) {
            unsigned short hi = f2bf(f[j]);
            float lo = f[j] - bf2f(hi);
            ahi[kc][j] = (short)hi;
            alo[kc][j] = (short)f2bf(lo);
        }
    }

    floatx4 acc[4] = {{0.f,0.f,0.f,0.f},{0.f,0.f,0.f,0.f},{0.f,0.f,0.f,0.f},{0.f,0.f,0.f,0.f}};
    #pragma unroll
    for (int kc = 0; kc < 4; ++kc) {
        #pragma unroll
        for (int nt = 0; nt < 4; ++nt) {
            int fo = ((kc * 4 + nt) * 64 + lane) * 8;
            short8 bhi = *(const short8*)&bhi_lds[fo];
            short8 blo = *(const short8*)&blo_lds[fo];
            acc[nt] = __builtin_amdgcn_mfma_f32_16x16x32_bf16(ahi[kc], bhi, acc[nt], 0, 0, 0);
            acc[nt] = __builtin_amdgcn_mfma_f32_16x16x32_bf16(ahi[kc], blo, acc[nt], 0, 0, 0);
            acc[nt] = __builtin_amdgcn_mfma_f32_16x16x32_bf16(alo[kc], bhi, acc[nt], 0, 0, 0);
        }
    }

    float dv[4];
    #pragma unroll
    for (int r = 0; r < 4; ++r) dv[r] = dinv[mbase + quad * 4 + r];
    #pragma unroll
    for (int nt = 0; nt < 4; ++nt) {
        int col = nt * 16 + m;
        #pragma unroll
        for (int r = 0; r < 4; ++r) {
            int row = mbase + quad * 4 + r;
            hs[row * D_H + col] = f2bf(acc[nt][r] * dv[r]);
        }
    }
}

// relu_buf[i][c] = relu(dinv[i]*(hs[i][c] + sum_{j->i} hs[j][c]) + b1[c])
// One wave per node, lane = feature. Edge loop unrolled x8 for MLP.
__global__ __launch_bounds__(256) void agg1_kernel(const unsigned short* __restrict__ hs,
                                                   const int* __restrict__ offsets,
                                                   const int* __restrict__ srcs,
                                                   const float* __restrict__ dinv,
                                                   const float* __restrict__ b1,
                                                   float* __restrict__ relu_buf) {
    int wave = (blockIdx.x * blockDim.x + threadIdx.x) >> 6;
    int lane = threadIdx.x & 63;
    int nwaves = (gridDim.x * blockDim.x) >> 6;
    for (int node = wave; node < N_NODES; node += nwaves) {
        int beg = offsets[node], end = offsets[node + 1];
        float acc = bf2f(hs[node * D_H + lane]);  // self loop
        int e = beg;
        for (; e + 8 <= end; e += 8) {
            int j0 = srcs[e + 0], j1 = srcs[e + 1], j2 = srcs[e + 2], j3 = srcs[e + 3];
            int j4 = srcs[e + 4], j5 = srcs[e + 5], j6 = srcs[e + 6], j7 = srcs[e + 7];
            float v0 = bf2f(hs[j0 * D_H + lane]);
            float v1 = bf2f(hs[j1 * D_H + lane]);
            float v2 = bf2f(hs[j2 * D_H + lane]);
            float v3 = bf2f(hs[j3 * D_H + lane]);
            float v4 = bf2f(hs[j4 * D_H + lane]);
            float v5 = bf2f(hs[j5 * D_H + lane]);
            float v6 = bf2f(hs[j6 * D_H + lane]);
            float v7 = bf2f(hs[j7 * D_H + lane]);
            acc += ((v0 + v1) + (v2 + v3)) + ((v4 + v5) + (v6 + v7));
        }
        for (; e < end; ++e) {
            acc += bf2f(hs[srcs[e] * D_H + lane]);
        }
        float v = acc * dinv[node] + b1[lane];
        relu_buf[node * D_H + lane] = fmaxf(v, 0.f);
    }
}

// h2s[i][c] = dinv[i] * sum_d relu_buf[i][d] * W2[d][c]
__global__ __launch_bounds__(256) void gemm2_kernel(const float* __restrict__ relu_buf,
                                                    const float* __restrict__ W2,
                                                    const float* __restrict__ dinv,
                                                    float* __restrict__ h2s) {
    __shared__ float W2s[D_H * D_OUT];  // 4 KB
    for (int i = threadIdx.x; i < D_H * D_OUT; i += 256) W2s[i] = W2[i];
    __syncthreads();
    int col = threadIdx.x & 15;
    int nidx = (blockIdx.x * blockDim.x + threadIdx.x) >> 4;
    int stride = (gridDim.x * blockDim.x) >> 4;
    for (int node = nidx; node < N_NODES; node += stride) {
        const float4* r4 = (const float4*)(relu_buf + node * D_H);
        float acc = 0.f;
        #pragma unroll
        for (int q = 0; q < 16; ++q) {
            float4 rv = r4[q];
            acc += rv.x * W2s[(4 * q + 0) * D_OUT + col];
            acc += rv.y * W2s[(4 * q + 1) * D_OUT + col];
            acc += rv.z * W2s[(4 * q + 2) * D_OUT + col];
            acc += rv.w * W2s[(4 * q + 3) * D_OUT + col];
        }
        h2s[node * D_OUT + col] = acc * dinv[node];
    }
}

// out[i][c] = dinv[i]*(h2s[i][c] + sum_{j->i} h2s[j][c]) + b2[c]
// 16 threads per node; edge loop unrolled x8.
__global__ __launch_bounds__(256) void agg2_kernel(const float* __restrict__ h2s,
                                                   const int* __restrict__ offsets,
                                                   const int* __restrict__ srcs,
                                                   const float* __restrict__ dinv,
                                                   const float* __restrict__ b2,
                                                   float* __restrict__ out) {
    int col = threadIdx.x & 15;
    int nidx = (blockIdx.x * blockDim.x + threadIdx.x) >> 4;
    int stride = (gridDim.x * blockDim.x) >> 4;
    for (int node = nidx; node < N_NODES; node += stride) {
        int beg = offsets[node], end = offsets[node + 1];
        float acc = h2s[node * D_OUT + col];  // self loop
        int e = beg;
        for (; e + 8 <= end; e += 8) {
            int j0 = srcs[e + 0], j1 = srcs[e + 1], j2 = srcs[e + 2], j3 = srcs[e + 3];
            int j4 = srcs[e + 4], j5 = srcs[e + 5], j6 = srcs[e + 6], j7 = srcs[e + 7];
            float v0 = h2s[j0 * D_OUT + col];
            float v1 = h2s[j1 * D_OUT + col];
            float v2 = h2s[j2 * D_OUT + col];
            float v3 = h2s[j3 * D_OUT + col];
            float v4 = h2s[j4 * D_OUT + col];
            float v5 = h2s[j5 * D_OUT + col];
            float v6 = h2s[j6 * D_OUT + col];
            float v7 = h2s[j7 * D_OUT + col];
            acc += ((v0 + v1) + (v2 + v3)) + ((v4 + v5) + (v6 + v7));
        }
        for (; e < end; ++e) {
            acc += h2s[srcs[e] * D_OUT + col];
        }
        out[node * D_OUT + col] = acc * dinv[node] + b2[col];
    }
}

extern "C" void kernel_launch(void* const* d_in, const int* in_sizes, int n_in,
                              void* d_out, int out_size, void* d_ws, size_t ws_size,
                              hipStream_t stream) {
    const float* x  = (const float*)d_in[0];
    const int*   ei = (const int*)d_in[1];
    const float* W1 = (const float*)d_in[2];
    const float* b1 = (const float*)d_in[3];
    const float* W2 = (const float*)d_in[4];
    const float* b2 = (const float*)d_in[5];
    float* out = (float*)d_out;

    const int* src = ei;             // edge_index[0]
    const int* dst = ei + N_EDGES;   // edge_index[1]

    char* w = (char*)d_ws;
    int*   counts   = (int*)(w + 0);
    int*   offsets  = (int*)(w + 400128);
    int*   cursors  = (int*)(w + 800256);
    float* dinv     = (float*)(w + 1200256);
    int*   srcs     = (int*)(w + 1600256);
    unsigned short* hs = (unsigned short*)(w + 8000256);
    float* relu_buf = (float*)(w + 20800256);
    float* h2s      = (float*)(w + 46400256);
    int*   bsums    = (int*)(w + 52800256);

    zero_kernel<<<(N_NODES + 255) / 256, 256, 0, stream>>>(counts, N_NODES);
    hist_kernel<<<2048, 256, 0, stream>>>(dst, counts);
    blocksum_kernel<<<NB_SCAN, 256, 0, stream>>>(counts, bsums);
    scan_bsums_kernel<<<1, 512, 0, stream>>>(bsums);
    scan_apply_kernel<<<NB_SCAN, 256, 0, stream>>>(counts, bsums, offsets, cursors, dinv);
    scatter_kernel<<<2048, 256, 0, stream>>>(src, dst, cursors, srcs);
    gemm1_mfma_kernel<<<(M_TILES + 3) / 4, 256, 0, stream>>>(x, W1, dinv, hs);
    agg1_kernel<<<6250, 256, 0, stream>>>(hs, offsets, srcs, dinv, b1, relu_buf);
    gemm2_kernel<<<6250, 256, 0, stream>>>(relu_buf, W2, dinv, h2s);
    agg2_kernel<<<6250, 256, 0, stream>>>(h2s, offsets, srcs, dinv, b2, out);
}